// Round 12
// baseline (468.192 us; speedup 1.0000x reference)
//
#include <hip/hip_runtime.h>
#include <math.h>

#define NGRID 32768   // 32^3 latent grid points
#define NOUT  16384   // output queries
#define CCH   256     // latent channels
#define H1DIM 512     // hidden width layer 1
#define TE    32      // edges per block
#define NTHR  256     // 4 waves

typedef _Float16 f16x8 __attribute__((ext_vector_type(8)));
typedef float    f32x16 __attribute__((ext_vector_type(16)));

__device__ __forceinline__ unsigned short f32_to_f16_bits(float v) {
    _Float16 h = (_Float16)v;
    return __builtin_bit_cast(unsigned short, h);
}
__device__ __forceinline__ float h2l(unsigned u) {
    return (float)__builtin_bit_cast(_Float16, (unsigned short)(u & 0xffff));
}
__device__ __forceinline__ float h2h(unsigned u) {
    return (float)__builtin_bit_cast(_Float16, (unsigned short)(u >> 16));
}

// gelu(x) = 0.5 x (1 + erf(x/sqrt2)), erf via A&S 7.1.26 (|err|<1.5e-7)
__device__ __forceinline__ float gelu_fast(float x) {
    float ax = fabsf(x) * 0.70710678118654752f;
    float t  = __builtin_amdgcn_rcpf(fmaf(0.3275911f, ax, 1.0f));
    float p  = fmaf(fmaf(fmaf(fmaf(1.061405429f, t, -1.453152027f), t, 1.421413741f), t,
                         -0.284496736f), t, 0.254829592f) * t;
    float e  = __expf(-ax * ax);
    float er = fmaf(-p, e, 1.0f);
    er = (x >= 0.0f) ? er : -er;
    return 0.5f * x * (1.0f + er);
}

// Pack W2 (512x256) and W3 (256x256) into 32x32x16 A-fragment order, f16.
// Flat: [ks][g(8)][lane(64)][j(8)] ; ch = g*32 + (l&31), k = ks*16 + (l>>5)*8 + j.
__global__ __launch_bounds__(256) void gino_pack_kernel(
    const float* __restrict__ W2, const float* __restrict__ W3,
    unsigned short* __restrict__ W2F, unsigned short* __restrict__ W3F)
{
    int idx = blockIdx.x * 256 + threadIdx.x;
    if (idx < 32 * 8 * 64) {          // W2F: ks 0..31
        int l = idx & 63, g = (idx >> 6) & 7, ks = idx >> 9;
        int ch = g * 32 + (l & 31);
        int k0 = ks * 16 + (l >> 5) * 8;
        unsigned int u[4];
        #pragma unroll
        for (int p = 0; p < 4; ++p) {
            unsigned int lo = f32_to_f16_bits(W2[(k0 + 2 * p) * CCH + ch]);
            unsigned int hh = f32_to_f16_bits(W2[(k0 + 2 * p + 1) * CCH + ch]);
            u[p] = lo | (hh << 16);
        }
        *(uint4*)(W2F + idx * 8) = make_uint4(u[0], u[1], u[2], u[3]);
    } else if (idx < 32 * 8 * 64 + 16 * 8 * 64) {   // W3F: ks 0..15
        int i2 = idx - 32 * 8 * 64;
        int l = i2 & 63, g = (i2 >> 6) & 7, ks = i2 >> 9;
        int ch = g * 32 + (l & 31);
        int k0 = ks * 16 + (l >> 5) * 8;
        unsigned int u[4];
        #pragma unroll
        for (int p = 0; p < 4; ++p) {
            unsigned int lo = f32_to_f16_bits(W3[(k0 + 2 * p) * CCH + ch]);
            unsigned int hh = f32_to_f16_bits(W3[(k0 + 2 * p + 1) * CCH + ch]);
            u[p] = lo | (hh << 16);
        }
        *(uint4*)(W3F + i2 * 8) = make_uint4(u[0], u[1], u[2], u[3]);
    }
}

// Convert latent_embed (2*32768*256 f32) to f16; 8 elems/thread.
__global__ __launch_bounds__(256) void gino_embed_f16_kernel(
    const float* __restrict__ in, unsigned short* __restrict__ out)
{
    int i = (blockIdx.x * 256 + threadIdx.x) * 8;
    float4 a = *(const float4*)(in + i);
    float4 b = *(const float4*)(in + i + 4);
    unsigned u0 = (unsigned)f32_to_f16_bits(a.x) | ((unsigned)f32_to_f16_bits(a.y) << 16);
    unsigned u1 = (unsigned)f32_to_f16_bits(a.z) | ((unsigned)f32_to_f16_bits(a.w) << 16);
    unsigned u2 = (unsigned)f32_to_f16_bits(b.x) | ((unsigned)f32_to_f16_bits(b.y) << 16);
    unsigned u3 = (unsigned)f32_to_f16_bits(b.z) | ((unsigned)f32_to_f16_bits(b.w) << 16);
    *(uint4*)(out + i) = make_uint4(u0, u1, u2, u3);
}

template <int F16E>
__global__ __launch_bounds__(NTHR, 4) void gino_edge_kernel(
    const float* __restrict__ latent_embed,   // (2, 32768, 256) f32
    const unsigned short* __restrict__ fembed,// (2, 32768, 256) f16 (if F16E)
    const float* __restrict__ latent_queries,
    const float* __restrict__ output_queries,
    const int*   __restrict__ nb_index,
    const int*   __restrict__ out_index,
    const float* __restrict__ W1, const float* __restrict__ b1,
    const float* __restrict__ b2, const float* __restrict__ b3,
    const unsigned short* __restrict__ W2F,
    const unsigned short* __restrict__ W3F,
    const float* __restrict__ Wp,
    float* __restrict__ sums, float* __restrict__ cnt, int E)
{
    __shared__ __align__(16) unsigned char s_h1[TE * 256];  // 8KB  h1 chunk f16 swz
    __shared__ __align__(16) unsigned char s_h2[TE * 512];  // 16KB h2 f16 swz
    __shared__ float s_agg[TE][8];
    __shared__ float s_pm[TE][8];
    __shared__ int s_nb[TE], s_oi[TE], s_valid[TE];

    const int tid = threadIdx.x;
    const int e0  = blockIdx.x * TE;

    // ---- Phase 0 ----
    ((float*)s_pm)[tid] = 0.0f;
    if (tid < TE) {
        int e     = e0 + tid;
        int valid = (e < E) ? 1 : 0;
        int ec    = valid ? e : (E - 1);
        int nb    = nb_index[ec];
        int oi    = out_index[ec];
        s_nb[tid] = nb; s_oi[tid] = oi; s_valid[tid] = valid;
        s_agg[tid][0] = latent_queries[nb * 3 + 0];
        s_agg[tid][1] = latent_queries[nb * 3 + 1];
        s_agg[tid][2] = latent_queries[nb * 3 + 2];
        s_agg[tid][3] = output_queries[oi * 3 + 0];
        s_agg[tid][4] = output_queries[oi * 3 + 1];
        s_agg[tid][5] = output_queries[oi * 3 + 2];
        if (valid) atomicAdd(&cnt[oi], 1.0f);
    }
    __syncthreads();

    const int l  = tid & 63;
    const int w  = tid >> 6;      // wave id 0..3; owns channel groups w and w+4
    const int le = l & 31;
    const int hi = l >> 5;
    const unsigned bsw1 = (unsigned)(le & 15) << 4;   // s_h1 rows 256B -> 16 slots
    const unsigned bsw2 = (unsigned)(le & 31) << 4;   // s_h2 rows 512B -> 32 slots
    const int g0 = w, g1 = w + 4;

    f32x16 acc0 = {}, acc1 = {};   // layer-2 accum: group g0 / group g1 (one edge tile)

    // ---- Phases 1+2 over four 128-col K-chunks of h1 ----
    #pragma unroll
    for (int c = 0; c < 4; ++c) {
        // Batch-issue BOTH groups' A-frags; they complete under phase-1 VALU.
        const unsigned short* gw0 = W2F + (size_t)(c * 8) * 4096 + g0 * 512 + l * 8;
        const unsigned short* gw1 = W2F + (size_t)(c * 8) * 4096 + g1 * 512 + l * 8;
        f16x8 aP[8], aQ[8];
        #pragma unroll
        for (int ks = 0; ks < 8; ++ks) {
            aP[ks] = *(const f16x8*)(gw0 + (size_t)ks * 4096);
            aQ[ks] = *(const f16x8*)(gw1 + (size_t)ks * 4096);
        }
        __builtin_amdgcn_sched_barrier(0);

        // Phase 1: h1 cols [c*128, c*128+128); lane owns 2 cols, wave owns 8 edges
        {
            const int col = c * 128 + l * 2;
            float w0[6], w1v[6];
            #pragma unroll
            for (int i = 0; i < 6; ++i) {
                float2 t2 = *(const float2*)(W1 + i * H1DIM + col);
                w0[i] = t2.x; w1v[i] = t2.y;
            }
            float2 bb = *(const float2*)(b1 + col);
            #pragma unroll
            for (int ee = 0; ee < 8; ++ee) {
                int e = w * 8 + ee;
                float v0 = bb.x, v1 = bb.y;
                #pragma unroll
                for (int i = 0; i < 6; ++i) {
                    float av = s_agg[e][i];
                    v0 = fmaf(av, w0[i], v0);
                    v1 = fmaf(av, w1v[i], v1);
                }
                unsigned u = (unsigned)f32_to_f16_bits(gelu_fast(v0)) |
                             ((unsigned)f32_to_f16_bits(gelu_fast(v1)) << 16);
                *(unsigned*)(s_h1 + e * 256 + (((unsigned)(l * 4)) ^ (((unsigned)(e & 15)) << 4))) = u;
            }
        }
        __syncthreads();

        // Phase 2: 8 K-steps; ONE B read feeds BOTH groups' MFMAs
        #pragma unroll
        for (int ks = 0; ks < 8; ++ks) {
            f16x8 b = *(const f16x8*)(s_h1 + le * 256 +
                          (((unsigned)(ks * 32 + hi * 16)) ^ bsw1));
            acc0 = __builtin_amdgcn_mfma_f32_32x32x16_f16(aP[ks], b, acc0, 0, 0, 0);
            acc1 = __builtin_amdgcn_mfma_f32_32x32x16_f16(aQ[ks], b, acc1, 0, 0, 0);
        }
        __syncthreads();
    }

    // ---- W3 A-frags for g0 (all 16 ks); complete under the epilogue VALU ----
    f16x8 a3P[8], a3Q[8];
    #pragma unroll
    for (int ks = 0; ks < 8; ++ks) {
        a3P[ks] = *(const f16x8*)(W3F + (size_t)ks * 4096 + g0 * 512 + l * 8);
        a3Q[ks] = *(const f16x8*)(W3F + (size_t)(8 + ks) * 4096 + g0 * 512 + l * 8);
    }
    __builtin_amdgcn_sched_barrier(0);

    // ---- Epilogue: h2 = gelu(acc + b2) -> s_h2 (row = edge le); acc dies ----
    #pragma unroll
    for (int gi = 0; gi < 2; ++gi) {
        int g = w + gi * 4;
        #pragma unroll
        for (int q = 0; q < 4; ++q) {
            int ch0 = g * 32 + q * 8 + hi * 4;
            float4 bb = *(const float4*)(b2 + ch0);
            float v0 = (gi ? acc1[q * 4 + 0] : acc0[q * 4 + 0]) + bb.x;
            float v1 = (gi ? acc1[q * 4 + 1] : acc0[q * 4 + 1]) + bb.y;
            float v2 = (gi ? acc1[q * 4 + 2] : acc0[q * 4 + 2]) + bb.z;
            float v3 = (gi ? acc1[q * 4 + 3] : acc0[q * 4 + 3]) + bb.w;
            unsigned u0 = f32_to_f16_bits(gelu_fast(v0)) |
                          ((unsigned)f32_to_f16_bits(gelu_fast(v1)) << 16);
            unsigned u1 = f32_to_f16_bits(gelu_fast(v2)) |
                          ((unsigned)f32_to_f16_bits(gelu_fast(v3)) << 16);
            *(uint2*)(s_h2 + le * 512 + (((unsigned)(ch0 * 2)) ^ bsw2)) = make_uint2(u0, u1);
        }
    }
    __syncthreads();

    // ---- Prefetch f rows for g0 channels of edge le; covered by phase-3 MFMA ----
    const int nb0 = s_nb[le];
    const int cb0 = g0 * 32 + hi * 4, cb1 = g1 * 32 + hi * 4;
    float4 fF0[8]; uint2 fH0[8];
    if constexpr (F16E) {
        const unsigned short* fp = fembed + (size_t)nb0 * CCH;
        #pragma unroll
        for (int q = 0; q < 4; ++q) {
            fH0[q]     = *(const uint2*)(fp + cb0 + q * 8);
            fH0[4 + q] = *(const uint2*)(fp + (size_t)NGRID * CCH + cb0 + q * 8);
        }
    } else {
        const float* fp = latent_embed + (size_t)nb0 * CCH;
        #pragma unroll
        for (int q = 0; q < 4; ++q) {
            fF0[q]     = *(const float4*)(fp + cb0 + q * 8);
            fF0[4 + q] = *(const float4*)(fp + (size_t)NGRID * CCH + cb0 + q * 8);
        }
    }
    __builtin_amdgcn_sched_barrier(0);

    // ---- Phase 3: k = h2 @ W3 + b3. Group g0 (kc0) then g1 (kc1); A reloads
    // and the g1 f-prefetch are covered by the preceding MFMA runs. ----
    f32x16 kc0 = {}, kc1 = {};
    #pragma unroll
    for (int ks = 0; ks < 8; ++ks) {
        f16x8 b = *(const f16x8*)(s_h2 + le * 512 +
                      (((unsigned)(ks * 32 + hi * 16)) ^ bsw2));
        kc0 = __builtin_amdgcn_mfma_f32_32x32x16_f16(a3P[ks], b, kc0, 0, 0, 0);
    }
    #pragma unroll
    for (int ks = 0; ks < 8; ++ks)   // reload a3P <- g1 ks 0..7 (covered by next loop)
        a3P[ks] = *(const f16x8*)(W3F + (size_t)ks * 4096 + g1 * 512 + l * 8);
    float4 fF1[8]; uint2 fH1[8];
    if constexpr (F16E) {
        const unsigned short* fp = fembed + (size_t)nb0 * CCH;
        #pragma unroll
        for (int q = 0; q < 4; ++q) {
            fH1[q]     = *(const uint2*)(fp + cb1 + q * 8);
            fH1[4 + q] = *(const uint2*)(fp + (size_t)NGRID * CCH + cb1 + q * 8);
        }
    } else {
        const float* fp = latent_embed + (size_t)nb0 * CCH;
        #pragma unroll
        for (int q = 0; q < 4; ++q) {
            fF1[q]     = *(const float4*)(fp + cb1 + q * 8);
            fF1[4 + q] = *(const float4*)(fp + (size_t)NGRID * CCH + cb1 + q * 8);
        }
    }
    __builtin_amdgcn_sched_barrier(0);
    #pragma unroll
    for (int ks = 0; ks < 8; ++ks) {
        f16x8 b = *(const f16x8*)(s_h2 + le * 512 +
                      (((unsigned)((8 + ks) * 32 + hi * 16)) ^ bsw2));
        kc0 = __builtin_amdgcn_mfma_f32_32x32x16_f16(a3Q[ks], b, kc0, 0, 0, 0);
    }
    #pragma unroll
    for (int ks = 0; ks < 8; ++ks)   // reload a3Q <- g1 ks 8..15
        a3Q[ks] = *(const f16x8*)(W3F + (size_t)(8 + ks) * 4096 + g1 * 512 + l * 8);
    __builtin_amdgcn_sched_barrier(0);
    #pragma unroll
    for (int ks = 0; ks < 8; ++ks) {
        f16x8 b = *(const f16x8*)(s_h2 + le * 512 +
                      (((unsigned)(ks * 32 + hi * 16)) ^ bsw2));
        kc1 = __builtin_amdgcn_mfma_f32_32x32x16_f16(a3P[ks], b, kc1, 0, 0, 0);
    }
    #pragma unroll
    for (int ks = 0; ks < 8; ++ks) {
        f16x8 b = *(const f16x8*)(s_h2 + le * 512 +
                      (((unsigned)((8 + ks) * 32 + hi * 16)) ^ bsw2));
        kc1 = __builtin_amdgcn_mfma_f32_32x32x16_f16(a3Q[ks], b, kc1, 0, 0, 0);
    }

    // ---- Phase 4: dot k (64 channels, both groups) with f and Wp; fold; LDS atomics ----
    {
        float pm[8] = {0.f, 0.f, 0.f, 0.f, 0.f, 0.f, 0.f, 0.f};
        #pragma unroll
        for (int gi = 0; gi < 2; ++gi) {
            int cb = gi ? cb1 : cb0;
            #pragma unroll
            for (int q = 0; q < 4; ++q) {
                int ch0 = cb + q * 8;
                float4 bb = *(const float4*)(b3 + ch0);
                float kv0 = (gi ? kc1[q * 4 + 0] : kc0[q * 4 + 0]) + bb.x;
                float kv1 = (gi ? kc1[q * 4 + 1] : kc0[q * 4 + 1]) + bb.y;
                float kv2 = (gi ? kc1[q * 4 + 2] : kc0[q * 4 + 2]) + bb.z;
                float kv3 = (gi ? kc1[q * 4 + 3] : kc0[q * 4 + 3]) + bb.w;
                float4 f0, f1;
                if constexpr (F16E) {
                    uint2 u0 = gi ? fH1[q] : fH0[q];
                    uint2 u1 = gi ? fH1[4 + q] : fH0[4 + q];
                    f0 = make_float4(h2l(u0.x), h2h(u0.x), h2l(u0.y), h2h(u0.y));
                    f1 = make_float4(h2l(u1.x), h2h(u1.x), h2l(u1.y), h2h(u1.y));
                } else {
                    f0 = gi ? fF1[q] : fF0[q];
                    f1 = gi ? fF1[4 + q] : fF0[4 + q];
                }
                float4 wp0 = *(const float4*)(Wp + (ch0 + 0) * 4);
                float4 wp1 = *(const float4*)(Wp + (ch0 + 1) * 4);
                float4 wp2 = *(const float4*)(Wp + (ch0 + 2) * 4);
                float4 wp3 = *(const float4*)(Wp + (ch0 + 3) * 4);
                float t0 = kv0 * f0.x, t1 = kv1 * f0.y, t2v = kv2 * f0.z, t3 = kv3 * f0.w;
                pm[0] = fmaf(t0, wp0.x, fmaf(t1, wp1.x, fmaf(t2v, wp2.x, fmaf(t3, wp3.x, pm[0]))));
                pm[1] = fmaf(t0, wp0.y, fmaf(t1, wp1.y, fmaf(t2v, wp2.y, fmaf(t3, wp3.y, pm[1]))));
                pm[2] = fmaf(t0, wp0.z, fmaf(t1, wp1.z, fmaf(t2v, wp2.z, fmaf(t3, wp3.z, pm[2]))));
                pm[3] = fmaf(t0, wp0.w, fmaf(t1, wp1.w, fmaf(t2v, wp2.w, fmaf(t3, wp3.w, pm[3]))));
                float s0 = kv0 * f1.x, s1 = kv1 * f1.y, s2 = kv2 * f1.z, s3 = kv3 * f1.w;
                pm[4] = fmaf(s0, wp0.x, fmaf(s1, wp1.x, fmaf(s2, wp2.x, fmaf(s3, wp3.x, pm[4]))));
                pm[5] = fmaf(s0, wp0.y, fmaf(s1, wp1.y, fmaf(s2, wp2.y, fmaf(s3, wp3.y, pm[5]))));
                pm[6] = fmaf(s0, wp0.z, fmaf(s1, wp1.z, fmaf(s2, wp2.z, fmaf(s3, wp3.z, pm[6]))));
                pm[7] = fmaf(s0, wp0.w, fmaf(s1, wp1.w, fmaf(s2, wp2.w, fmaf(s3, wp3.w, pm[7]))));
            }
        }
        #pragma unroll
        for (int v = 0; v < 8; ++v) pm[v] += __shfl_xor(pm[v], 32);
        if (hi == 0) {
            #pragma unroll
            for (int v = 0; v < 8; ++v) atomicAdd(&s_pm[le][v], pm[v]);
        }
    }
    __syncthreads();

    // ---- Drain: one global atomic per thread ----
    {
        int el = tid >> 3;
        int v  = tid & 7;
        if (s_valid[el]) {
            int b  = v >> 2;
            int oc = v & 3;
            atomicAdd(&sums[((size_t)b * NOUT + s_oi[el]) * 4 + oc], s_pm[el][v]);
        }
    }
}

__global__ __launch_bounds__(256) void gino_finalize_kernel(
    const float* __restrict__ sums,
    const float* __restrict__ cnt,
    const float* __restrict__ bp,
    float* __restrict__ out)
{
    int idx = blockIdx.x * 256 + threadIdx.x;
    if (idx >= 2 * NOUT * 4) return;
    int oc = idx & 3;
    int i  = (idx >> 2) & (NOUT - 1);
    float c = fmaxf(cnt[i], 1.0f);
    out[idx] = sums[idx] / c + bp[oc];
}

extern "C" void kernel_launch(void* const* d_in, const int* in_sizes, int n_in,
                              void* d_out, int out_size, void* d_ws, size_t ws_size,
                              hipStream_t stream) {
    const float* latent_embed   = (const float*)d_in[0];
    const float* latent_queries = (const float*)d_in[1];
    const float* output_queries = (const float*)d_in[2];
    const int*   nb_index       = (const int*)d_in[3];
    const int*   out_index      = (const int*)d_in[4];
    const float* W1 = (const float*)d_in[5];
    const float* b1 = (const float*)d_in[6];
    const float* W2 = (const float*)d_in[7];
    const float* b2 = (const float*)d_in[8];
    const float* W3 = (const float*)d_in[9];
    const float* b3 = (const float*)d_in[10];
    const float* Wp = (const float*)d_in[11];
    const float* bp = (const float*)d_in[12];

    const int E = in_sizes[3];

    // ws layout: sums(512K) | cnt(64K) | W2F(256K) | W3F(128K) | fembed(32M f16)
    float* sums = (float*)d_ws;
    float* cnt  = sums + 2 * NOUT * 4;
    unsigned short* W2F = (unsigned short*)(cnt + NOUT);
    unsigned short* W3F = W2F + 32 * 8 * 64 * 8;
    unsigned short* fembed = W3F + 16 * 8 * 64 * 8;
    const size_t base_bytes = (size_t)((char*)fembed - (char*)d_ws);
    const size_t femb_bytes = (size_t)2 * NGRID * CCH * 2;
    const bool use_f16 = ws_size >= base_bytes + femb_bytes;

    hipMemsetAsync(d_ws, 0, (size_t)(2 * NOUT * 4 + NOUT) * sizeof(float), stream);

    gino_pack_kernel<<<(32 * 8 * 64 + 16 * 8 * 64 + 255) / 256, 256, 0, stream>>>(
        W2, W3, W2F, W3F);

    int nblk = (E + TE - 1) / TE;
    if (use_f16) {
        gino_embed_f16_kernel<<<(2 * NGRID * CCH / 8 + 255) / 256, 256, 0, stream>>>(
            latent_embed, fembed);
        gino_edge_kernel<1><<<nblk, NTHR, 0, stream>>>(
            latent_embed, fembed, latent_queries, output_queries, nb_index, out_index,
            W1, b1, b2, b3, W2F, W3F, Wp, sums, cnt, E);
    } else {
        gino_edge_kernel<0><<<nblk, NTHR, 0, stream>>>(
            latent_embed, (const unsigned short*)nullptr, latent_queries, output_queries,
            nb_index, out_index, W1, b1, b2, b3, W2F, W3F, Wp, sums, cnt, E);
    }

    gino_finalize_kernel<<<(2 * NOUT * 4 + 255) / 256, 256, 0, stream>>>(
        sums, cnt, bp, (float*)d_out);
}

// Round 13
// 239.293 us; speedup vs baseline: 1.9566x; 1.9566x over previous
//
#include <hip/hip_runtime.h>
#include <math.h>

#define NGRID 32768   // 32^3 latent grid points
#define NOUT  16384   // output queries
#define CCH   256     // latent channels
#define H1DIM 512     // hidden width layer 1
#define TE    64      // edges per block
#define NTHR  512     // 8 waves

typedef _Float16 f16x8 __attribute__((ext_vector_type(8)));
typedef float    f32x16 __attribute__((ext_vector_type(16)));

__device__ __forceinline__ unsigned short f32_to_f16_bits(float v) {
    _Float16 h = (_Float16)v;
    return __builtin_bit_cast(unsigned short, h);
}

// gelu via tanh-form: x * sigmoid(2*sqrt(2/pi)*(x + 0.044715 x^3)).
// 8 VALU ops (native exp2 + rcp). |err vs exact erf-gelu| <= ~4e-4 abs.
__device__ __forceinline__ float gelu_fast(float x) {
    float x2 = x * x;
    float u  = x * fmaf(0.035677408f, x2, 0.7978845608f);
    float e  = __builtin_amdgcn_exp2f(u * -2.885390082f);   // exp(-2u)
    return x * __builtin_amdgcn_rcpf(1.0f + e);
}

// Pack W2 (512x256) and W3 (256x256) into 32x32x16 A-fragment order, f16.
// A[m=ch][k], frag lane l: m = l&31, k = ks*16 + (l>>5)*8 + j.
// Flat: [ks][g(8)][lane(64)][j(8)] ; ch = g*32 + (l&31).
__global__ __launch_bounds__(256) void gino_pack_kernel(
    const float* __restrict__ W2, const float* __restrict__ W3,
    unsigned short* __restrict__ W2F, unsigned short* __restrict__ W3F)
{
    int idx = blockIdx.x * 256 + threadIdx.x;
    if (idx < 32 * 8 * 64) {          // W2F: ks 0..31
        int l = idx & 63, g = (idx >> 6) & 7, ks = idx >> 9;
        int ch = g * 32 + (l & 31);
        int k0 = ks * 16 + (l >> 5) * 8;
        unsigned int u[4];
        #pragma unroll
        for (int p = 0; p < 4; ++p) {
            unsigned int lo = f32_to_f16_bits(W2[(k0 + 2 * p) * CCH + ch]);
            unsigned int hh = f32_to_f16_bits(W2[(k0 + 2 * p + 1) * CCH + ch]);
            u[p] = lo | (hh << 16);
        }
        *(uint4*)(W2F + idx * 8) = make_uint4(u[0], u[1], u[2], u[3]);
    } else if (idx < 32 * 8 * 64 + 16 * 8 * 64) {   // W3F: ks 0..15
        int i2 = idx - 32 * 8 * 64;
        int l = i2 & 63, g = (i2 >> 6) & 7, ks = i2 >> 9;
        int ch = g * 32 + (l & 31);
        int k0 = ks * 16 + (l >> 5) * 8;
        unsigned int u[4];
        #pragma unroll
        for (int p = 0; p < 4; ++p) {
            unsigned int lo = f32_to_f16_bits(W3[(k0 + 2 * p) * CCH + ch]);
            unsigned int hh = f32_to_f16_bits(W3[(k0 + 2 * p + 1) * CCH + ch]);
            u[p] = lo | (hh << 16);
        }
        *(uint4*)(W3F + i2 * 8) = make_uint4(u[0], u[1], u[2], u[3]);
    }
}

__global__ __launch_bounds__(NTHR, 4) void gino_edge_kernel(
    const float* __restrict__ latent_embed,   // (2, 32768, 256)
    const float* __restrict__ latent_queries, // (32768, 3)
    const float* __restrict__ output_queries, // (16384, 3)
    const int*   __restrict__ nb_index,
    const int*   __restrict__ out_index,
    const float* __restrict__ W1, const float* __restrict__ b1,
    const float* __restrict__ b2, const float* __restrict__ b3,
    const unsigned short* __restrict__ W2F,
    const unsigned short* __restrict__ W3F,
    const float* __restrict__ Wp,
    float* __restrict__ sums, float* __restrict__ cnt, int E)
{
    __shared__ __align__(16) unsigned char s_h1[TE * 256];  // h1 128-col chunk f16 swz (16KB)
    __shared__ __align__(16) unsigned char s_h2[TE * 512];  // h2 f16 swz (32KB)
    __shared__ float s_agg[TE][8];
    __shared__ float s_pm[TE][8];
    __shared__ int s_nb[TE], s_oi[TE], s_valid[TE];

    const int tid = threadIdx.x;
    const int e0  = blockIdx.x * TE;

    // ---- Phase 0 ----
    ((float*)s_pm)[tid] = 0.0f;
    if (tid < TE) {
        int e     = e0 + tid;
        int valid = (e < E) ? 1 : 0;
        int ec    = valid ? e : (E - 1);
        int nb    = nb_index[ec];
        int oi    = out_index[ec];
        s_nb[tid] = nb; s_oi[tid] = oi; s_valid[tid] = valid;
        s_agg[tid][0] = latent_queries[nb * 3 + 0];
        s_agg[tid][1] = latent_queries[nb * 3 + 1];
        s_agg[tid][2] = latent_queries[nb * 3 + 2];
        s_agg[tid][3] = output_queries[oi * 3 + 0];
        s_agg[tid][4] = output_queries[oi * 3 + 1];
        s_agg[tid][5] = output_queries[oi * 3 + 2];
        if (valid) atomicAdd(&cnt[oi], 1.0f);
    }
    __syncthreads();

    const int l  = tid & 63;
    const int w  = tid >> 6;      // wave id 0..7 == channel group g
    const int le = l & 31;
    const int hi = l >> 5;
    const unsigned bsw1 = (unsigned)(le & 15) << 4;   // s_h1 rows = 256B -> 16 slots
    const unsigned bsw2 = (unsigned)(le & 31) << 4;   // s_h2 rows = 512B -> 32 slots

    f32x16 acc0 = {}, acc1 = {};   // layer-2 accum: edge-tile 0 / edge-tile 1

    // ---- Phases 1+2 over four 128-col K-chunks of h1 ----
    #pragma unroll
    for (int c = 0; c < 4; ++c) {
        // Batch-issue this chunk's 8 A-fragments into VGPRs; they complete
        // under phase-1's VALU work. sched_barrier pins issue before phase 1.
        const unsigned short* gw = W2F + (size_t)(c * 8) * 4096 + w * 512 + l * 8;
        f16x8 a[8];
        #pragma unroll
        for (int ks = 0; ks < 8; ++ks)
            a[ks] = *(const f16x8*)(gw + (size_t)ks * 4096);
        __builtin_amdgcn_sched_barrier(0);

        // Phase 1: h1 cols [c*128, c*128+128) ; lane owns 2 cols, wave owns 8 edges
        {
            const int col = c * 128 + l * 2;
            float w0[6], w1v[6];
            #pragma unroll
            for (int i = 0; i < 6; ++i) {
                float2 t2 = *(const float2*)(W1 + i * H1DIM + col);
                w0[i] = t2.x; w1v[i] = t2.y;
            }
            float2 bb = *(const float2*)(b1 + col);
            #pragma unroll
            for (int ee = 0; ee < 8; ++ee) {
                int e = w * 8 + ee;
                float v0 = bb.x, v1 = bb.y;
                #pragma unroll
                for (int i = 0; i < 6; ++i) {
                    float av = s_agg[e][i];
                    v0 = fmaf(av, w0[i], v0);
                    v1 = fmaf(av, w1v[i], v1);
                }
                unsigned u = (unsigned)f32_to_f16_bits(gelu_fast(v0)) |
                             ((unsigned)f32_to_f16_bits(gelu_fast(v1)) << 16);
                *(unsigned*)(s_h1 + e * 256 + (((unsigned)(l * 4)) ^ (((unsigned)(e & 15)) << 4))) = u;
            }
        }
        __syncthreads();

        // Phase 2: 8 K-steps, A already in registers, B from swizzled LDS
        #pragma unroll
        for (int ks = 0; ks < 8; ++ks) {
            f16x8 b0 = *(const f16x8*)(s_h1 + le * 256 +
                           (((unsigned)(ks * 32 + hi * 16)) ^ bsw1));
            f16x8 b1f = *(const f16x8*)(s_h1 + (32 + le) * 256 +
                           (((unsigned)(ks * 32 + hi * 16)) ^ bsw1));
            acc0 = __builtin_amdgcn_mfma_f32_32x32x16_f16(a[ks], b0,  acc0, 0, 0, 0);
            acc1 = __builtin_amdgcn_mfma_f32_32x32x16_f16(a[ks], b1f, acc1, 0, 0, 0);
        }
        __syncthreads();   // s_h1 reads done before next chunk overwrites
    }

    // ---- Batch-issue all 16 W3 A-fragments; they complete under the epilogue ----
    const unsigned short* gw3 = W3F + w * 512 + l * 8;
    f16x8 a3[16];
    #pragma unroll
    for (int ks = 0; ks < 16; ++ks)
        a3[ks] = *(const f16x8*)(gw3 + (size_t)ks * 4096);
    __builtin_amdgcn_sched_barrier(0);

    // ---- Phase 2 epilogue: h2 = gelu(acc + b2) -> s_h2 ----
    // D: col=le (edge-in-tile), local ch = (reg&3)+8*(reg>>2)+4*hi
    #pragma unroll
    for (int t = 0; t < 2; ++t) {
        int erow = t * 32 + le;
        unsigned esw = (unsigned)(erow & 31) << 4;
        #pragma unroll
        for (int q = 0; q < 4; ++q) {
            int ch0 = w * 32 + q * 8 + hi * 4;
            float4 bb = *(const float4*)(b2 + ch0);
            float v0 = (t ? acc1[q * 4 + 0] : acc0[q * 4 + 0]) + bb.x;
            float v1 = (t ? acc1[q * 4 + 1] : acc0[q * 4 + 1]) + bb.y;
            float v2 = (t ? acc1[q * 4 + 2] : acc0[q * 4 + 2]) + bb.z;
            float v3 = (t ? acc1[q * 4 + 3] : acc0[q * 4 + 3]) + bb.w;
            unsigned int u0 = f32_to_f16_bits(gelu_fast(v0)) |
                              ((unsigned)f32_to_f16_bits(gelu_fast(v1)) << 16);
            unsigned int u1 = f32_to_f16_bits(gelu_fast(v2)) |
                              ((unsigned)f32_to_f16_bits(gelu_fast(v3)) << 16);
            *(uint2*)(s_h2 + erow * 512 + (((unsigned)(ch0 * 2)) ^ esw)) = make_uint2(u0, u1);
        }
    }
    __syncthreads();

    // ---- Phase 3: k = h2 @ W3 + b3 (k stays in registers), A in registers ----
    f32x16 kc0 = {}, kc1 = {};
    #pragma unroll
    for (int ks = 0; ks < 16; ++ks) {
        f16x8 b0 = *(const f16x8*)(s_h2 + le * 512 +
                       (((unsigned)(ks * 32 + hi * 16)) ^ bsw2));
        f16x8 b1f = *(const f16x8*)(s_h2 + (32 + le) * 512 +
                       (((unsigned)(ks * 32 + hi * 16)) ^ bsw2));
        kc0 = __builtin_amdgcn_mfma_f32_32x32x16_f16(a3[ks], b0,  kc0, 0, 0, 0);
        kc1 = __builtin_amdgcn_mfma_f32_32x32x16_f16(a3[ks], b1f, kc1, 0, 0, 0);
    }

    // ---- Phase 4: per edge-tile, dot k with f and Wp; hi-fold; LDS atomics ----
    #pragma unroll
    for (int t = 0; t < 2; ++t) {
        int e  = t * 32 + le;
        int nb = s_nb[e];
        const float* fb0 = latent_embed + (size_t)nb * CCH;
        const float* fb1 = latent_embed + ((size_t)NGRID + nb) * CCH;
        float pm[8] = {0.f, 0.f, 0.f, 0.f, 0.f, 0.f, 0.f, 0.f};
        #pragma unroll
        for (int q = 0; q < 4; ++q) {
            int ch0 = w * 32 + q * 8 + hi * 4;
            float4 bb = *(const float4*)(b3 + ch0);
            float kv0 = (t ? kc1[q * 4 + 0] : kc0[q * 4 + 0]) + bb.x;
            float kv1 = (t ? kc1[q * 4 + 1] : kc0[q * 4 + 1]) + bb.y;
            float kv2 = (t ? kc1[q * 4 + 2] : kc0[q * 4 + 2]) + bb.z;
            float kv3 = (t ? kc1[q * 4 + 3] : kc0[q * 4 + 3]) + bb.w;
            float4 f0 = *(const float4*)(fb0 + ch0);
            float4 f1 = *(const float4*)(fb1 + ch0);
            float4 wp0 = *(const float4*)(Wp + (ch0 + 0) * 4);
            float4 wp1 = *(const float4*)(Wp + (ch0 + 1) * 4);
            float4 wp2 = *(const float4*)(Wp + (ch0 + 2) * 4);
            float4 wp3 = *(const float4*)(Wp + (ch0 + 3) * 4);
            float t0 = kv0 * f0.x, t1 = kv1 * f0.y, t2v = kv2 * f0.z, t3 = kv3 * f0.w;
            pm[0] = fmaf(t0, wp0.x, fmaf(t1, wp1.x, fmaf(t2v, wp2.x, fmaf(t3, wp3.x, pm[0]))));
            pm[1] = fmaf(t0, wp0.y, fmaf(t1, wp1.y, fmaf(t2v, wp2.y, fmaf(t3, wp3.y, pm[1]))));
            pm[2] = fmaf(t0, wp0.z, fmaf(t1, wp1.z, fmaf(t2v, wp2.z, fmaf(t3, wp3.z, pm[2]))));
            pm[3] = fmaf(t0, wp0.w, fmaf(t1, wp1.w, fmaf(t2v, wp2.w, fmaf(t3, wp3.w, pm[3]))));
            float s0 = kv0 * f1.x, s1 = kv1 * f1.y, s2 = kv2 * f1.z, s3 = kv3 * f1.w;
            pm[4] = fmaf(s0, wp0.x, fmaf(s1, wp1.x, fmaf(s2, wp2.x, fmaf(s3, wp3.x, pm[4]))));
            pm[5] = fmaf(s0, wp0.y, fmaf(s1, wp1.y, fmaf(s2, wp2.y, fmaf(s3, wp3.y, pm[5]))));
            pm[6] = fmaf(s0, wp0.z, fmaf(s1, wp1.z, fmaf(s2, wp2.z, fmaf(s3, wp3.z, pm[6]))));
            pm[7] = fmaf(s0, wp0.w, fmaf(s1, wp1.w, fmaf(s2, wp2.w, fmaf(s3, wp3.w, pm[7]))));
        }
        #pragma unroll
        for (int v = 0; v < 8; ++v) pm[v] += __shfl_xor(pm[v], 32);
        if (hi == 0) {
            #pragma unroll
            for (int v = 0; v < 8; ++v) atomicAdd(&s_pm[e][v], pm[v]);
        }
    }
    __syncthreads();

    // ---- Drain: one global atomic per thread ----
    {
        int el = tid >> 3;
        int v  = tid & 7;
        if (s_valid[el]) {
            int b  = v >> 2;
            int oc = v & 3;
            atomicAdd(&sums[((size_t)b * NOUT + s_oi[el]) * 4 + oc], s_pm[el][v]);
        }
    }
}

__global__ __launch_bounds__(256) void gino_finalize_kernel(
    const float* __restrict__ sums,
    const float* __restrict__ cnt,
    const float* __restrict__ bp,
    float* __restrict__ out)
{
    int idx = blockIdx.x * 256 + threadIdx.x;
    if (idx >= 2 * NOUT * 4) return;
    int oc = idx & 3;
    int i  = (idx >> 2) & (NOUT - 1);
    float c = fmaxf(cnt[i], 1.0f);
    out[idx] = sums[idx] / c + bp[oc];
}

extern "C" void kernel_launch(void* const* d_in, const int* in_sizes, int n_in,
                              void* d_out, int out_size, void* d_ws, size_t ws_size,
                              hipStream_t stream) {
    const float* latent_embed   = (const float*)d_in[0];
    const float* latent_queries = (const float*)d_in[1];
    const float* output_queries = (const float*)d_in[2];
    const int*   nb_index       = (const int*)d_in[3];
    const int*   out_index      = (const int*)d_in[4];
    const float* W1 = (const float*)d_in[5];
    const float* b1 = (const float*)d_in[6];
    const float* W2 = (const float*)d_in[7];
    const float* b2 = (const float*)d_in[8];
    const float* W3 = (const float*)d_in[9];
    const float* b3 = (const float*)d_in[10];
    const float* Wp = (const float*)d_in[11];
    const float* bp = (const float*)d_in[12];

    const int E = in_sizes[3];

    float* sums = (float*)d_ws;                         // 2*16384*4 fp32  (512KB)
    float* cnt  = sums + 2 * NOUT * 4;                  // 16384 fp32      (64KB)
    unsigned short* W2F = (unsigned short*)(cnt + NOUT);// 32*8*64*8 f16   (256KB)
    unsigned short* W3F = W2F + 32 * 8 * 64 * 8;        // 16*8*64*8 f16   (128KB)

    hipMemsetAsync(d_ws, 0, (size_t)(2 * NOUT * 4 + NOUT) * sizeof(float), stream);

    gino_pack_kernel<<<(32 * 8 * 64 + 16 * 8 * 64 + 255) / 256, 256, 0, stream>>>(
        W2, W3, W2F, W3F);

    int nblk = (E + TE - 1) / TE;
    gino_edge_kernel<<<nblk, NTHR, 0, stream>>>(
        latent_embed, latent_queries, output_queries, nb_index, out_index,
        W1, b1, b2, b3, W2F, W3F, Wp, sums, cnt, E);

    gino_finalize_kernel<<<(2 * NOUT * 4 + 255) / 256, 256, 0, stream>>>(
        sums, cnt, bp, (float*)d_out);
}